// Round 11
// baseline (660.037 us; speedup 1.0000x reference)
//
#include <hip/hip_runtime.h>
#include <hip/hip_bf16.h>

typedef __bf16 bf16x8 __attribute__((ext_vector_type(8)));
typedef float f32x4 __attribute__((ext_vector_type(4)));
typedef unsigned short u16;
typedef unsigned int u32;

#define DEV __device__ __forceinline__
#define MFMA16 __builtin_amdgcn_mfma_f32_16x16x32_bf16

DEV u16 f2b(float f) {
  __hip_bfloat16 h = __float2bfloat16(f);
  return __builtin_bit_cast(u16, h);
}
DEV u32 pk2(float x, float y) { return (u32)f2b(x) | ((u32)f2b(y) << 16); }

DEV void gl_lds16(const u16* g, u16* l) {
  __builtin_amdgcn_global_load_lds(
      (const __attribute__((address_space(1))) void*)g,
      (__attribute__((address_space(3))) void*)l, 16, 0, 0);
}

// ---------------------------------------------------------------------------
// precvt: blocks 0..1023 = weight transpose+cvt (4 weights x 256 tiles);
//         blocks 1024..3071 = query f32->bf16.
// ---------------------------------------------------------------------------
__global__ __launch_bounds__(256) void precvt(
    const float* __restrict__ Wq, const float* __restrict__ Wk,
    const float* __restrict__ Wv, const float* __restrict__ Wo,
    u16* __restrict__ WtQ, u16* __restrict__ WtK,
    u16* __restrict__ WtV, u16* __restrict__ WtO,
    const float4* __restrict__ query, uint4* __restrict__ qc) {
  __shared__ u16 ls[64 * 80];
  const int t = threadIdx.x;
  const int bid = blockIdx.x;
  if (bid < 1024) {
    const int wsel = bid >> 8;
    const float* W = (wsel == 0) ? Wq : (wsel == 1) ? Wk : (wsel == 2) ? Wv : Wo;
    u16* Wt = (wsel == 0) ? WtQ : (wsel == 1) ? WtK : (wsel == 2) ? WtV : WtO;
    const int tb = bid & 255;
    const int bn = (tb & 15) << 6;
    const int bk = (tb >> 4) << 6;
#pragma unroll
    for (int rr = 0; rr < 4; ++rr) {
      const int r = (t >> 4) + (rr << 4);
      const int cc = (t & 15) << 2;
      const float4 v = *reinterpret_cast<const float4*>(&W[(size_t)(bk + r) * 1024 + bn + cc]);
      ls[(cc + 0) * 80 + r] = f2b(v.x);
      ls[(cc + 1) * 80 + r] = f2b(v.y);
      ls[(cc + 2) * 80 + r] = f2b(v.z);
      ls[(cc + 3) * 80 + r] = f2b(v.w);
    }
    __syncthreads();
#pragma unroll
    for (int it = 0; it < 2; ++it) {
      const int idx = t + (it << 8);
      const int n = idx >> 3, c8 = idx & 7;
      const uint4 o = *reinterpret_cast<const uint4*>(&ls[n * 80 + (c8 << 3)]);
      *reinterpret_cast<uint4*>(&Wt[(size_t)(bn + n) * 1024 + bk + (c8 << 3)]) = o;
    }
    return;
  }
  const int blk = bid - 1024;
#pragma unroll
  for (int j = 0; j < 4; ++j) {
    const size_t ci = (size_t)blk * 1024 + j * 256 + t;
    const float4 a = query[2 * ci];
    const float4 b = query[2 * ci + 1];
    uint4 o;
    o.x = pk2(a.x, a.y);
    o.y = pk2(a.z, a.w);
    o.z = pk2(b.x, b.y);
    o.w = pk2(b.z, b.w);
    qc[ci] = o;
  }
}

// ---------------------------------------------------------------------------
// 256x256-tile GEMM, 8 gemm waves (proven schedule, byte-identical) +
// optional 2 converter waves (DO_CVT).  Converter waves have their OWN
// per-wave vmcnt (cannot disturb the gemm counted-vmcnt schedule) and
// execute exactly the gemm waves' 130 s_barriers (1 + 8*16 + 1).
// KEY FIX vs round 9: __launch_bounds__(640, 1) not (640, 2) -- this GEMM
// is 1 block/CU anyway (128KB LDS); min-2-blocks capped VGPR at 84 and
// spilled the acc[8][4] (405MB scratch writes).  (640,1) -> 3 waves/SIMD
// -> cap 170 -> gemm path keeps 128 VGPR.
// ---------------------------------------------------------------------------
#define MF_CL(PR, PC, AF, BF)                                                  \
  asm volatile("s_waitcnt lgkmcnt(0)" ::: "memory");                           \
  __builtin_amdgcn_sched_barrier(0);                                           \
  __builtin_amdgcn_s_setprio(1);                                               \
  _Pragma("unroll") for (int i = 0; i < 4; ++i)                                \
  _Pragma("unroll") for (int j = 0; j < 2; ++j) {                              \
    acc[(PR)*4 + i][(PC)*2 + j] =                                              \
        MFMA16(AF[i][0], BF[j][0], acc[(PR)*4 + i][(PC)*2 + j], 0, 0, 0);      \
    acc[(PR)*4 + i][(PC)*2 + j] =                                              \
        MFMA16(AF[i][1], BF[j][1], acc[(PR)*4 + i][(PC)*2 + j], 0, 0, 0);      \
  }                                                                            \
  __builtin_amdgcn_s_setprio(0);

#define BAR()  __builtin_amdgcn_s_barrier()
#define SBAR() __builtin_amdgcn_sched_barrier(0)

template <int DO_CVT, int OUT_F32>
__global__ __launch_bounds__(DO_CVT ? 640 : 512, 1) void gemm256(
    const u16* __restrict__ A, const u16* __restrict__ Bt,
    const float* __restrict__ bias, void* __restrict__ Cp,
    const float4* __restrict__ csrc, uint2* __restrict__ cdst,
    const int M, const int N, const int K) {
  __shared__ u16 smem[65536];                       // 128 KiB
  u16* const AbA[2] = {smem, smem + 16384};         // 256x64 each
  u16* const BbA[2] = {smem + 32768, smem + 49152};
  const int NT = K >> 6;
  const int tid = threadIdx.x;
  const int lane = tid & 63;
  const int w = tid >> 6;
  const int c = lane & 15, g = lane >> 4;

  if (DO_CVT && w >= 8) {
    // ---- converter waves: 128 lanes, 65536 f32 per block, own vmcnt ----
    const int l = tid - 512;                        // 0..127
    const size_t b4 = (size_t)blockIdx.x * 16384 + l;  // float4 units
    float4 Ax = csrc[b4 + 0];
    float4 Bx = csrc[b4 + 128];
    float4 Cx = csrc[b4 + 256];
    float4 Dx = csrc[b4 + 384];
    BAR();                                          // match prologue barrier
    for (int s = 0; s < 128; s += 4) {
      uint2 o;
      o.x = pk2(Ax.x, Ax.y); o.y = pk2(Ax.z, Ax.w);
      cdst[b4 + (size_t)s * 128] = o;
      if (s < 124) Ax = csrc[b4 + (size_t)(s + 4) * 128];
      BAR();
      o.x = pk2(Bx.x, Bx.y); o.y = pk2(Bx.z, Bx.w);
      cdst[b4 + (size_t)(s + 1) * 128] = o;
      if (s < 124) Bx = csrc[b4 + (size_t)(s + 5) * 128];
      BAR();
      o.x = pk2(Cx.x, Cx.y); o.y = pk2(Cx.z, Cx.w);
      cdst[b4 + (size_t)(s + 2) * 128] = o;
      if (s < 124) Cx = csrc[b4 + (size_t)(s + 6) * 128];
      BAR();
      o.x = pk2(Dx.x, Dx.y); o.y = pk2(Dx.z, Dx.w);
      cdst[b4 + (size_t)(s + 3) * 128] = o;
      if (s < 124) Dx = csrc[b4 + (size_t)(s + 7) * 128];
      BAR();
    }
    BAR();                                          // match epilogue syncthreads
    return;
  }

  const int nwg = (int)gridDim.x;
  const int q = nwg >> 3, r = nwg & 7;
  const int xcd = (int)blockIdx.x & 7, loc = (int)blockIdx.x >> 3;
  const int bid = (xcd < r ? xcd * (q + 1) : r * (q + 1) + (xcd - r) * q) + loc;
  const int ntN = N >> 8;
  const int bm = bid / ntN, bn = bid - bm * ntN;
  const int m0 = bm << 8, n0 = bn << 8;

  const int rl = lane >> 3;
  const int swc = ((lane & 7) ^ rl) << 3;           // pre-swizzled source col (elems)
  const int wrow = w << 3;
  const int wm = (w >> 2) << 7, wn = (w & 3) << 6;

  auto stA64 = [&](int t, int row0) {
    u16* b = AbA[t & 1];
    gl_lds16(A + (size_t)(m0 + row0 + wrow + rl) * K + (t << 6) + swc,
             &b[(row0 + wrow) << 6]);
  };
  auto stB32 = [&](int t, int ra, int rb) {
    u16* b = BbA[t & 1];
    const int r0 = (w < 4) ? (ra + (w << 3)) : (rb + ((w - 4) << 3));
    gl_lds16(Bt + (size_t)(n0 + r0 + rl) * K + (t << 6) + swc, &b[r0 << 6]);
  };

  const int sK0 = (g ^ (c & 7)) << 3;
  const int sK1 = ((4 + g) ^ (c & 7)) << 3;
  auto rdA = [&](u16* Ac, int poff, bf16x8 (&dst)[4][2]) {
#pragma unroll
    for (int mi = 0; mi < 4; ++mi) {
      const int ro = (wm + poff + (mi << 4) + c) << 6;
      dst[mi][0] = *reinterpret_cast<const bf16x8*>(&Ac[ro + sK0]);
      dst[mi][1] = *reinterpret_cast<const bf16x8*>(&Ac[ro + sK1]);
    }
  };
  auto rdB = [&](u16* Bc, int poff, bf16x8 (&dst)[2][2]) {
#pragma unroll
    for (int ni = 0; ni < 2; ++ni) {
      const int ro = (wn + poff + (ni << 4) + c) << 6;
      dst[ni][0] = *reinterpret_cast<const bf16x8*>(&Bc[ro + sK0]);
      dst[ni][1] = *reinterpret_cast<const bf16x8*>(&Bc[ro + sK1]);
    }
  };

  f32x4 acc[8][4];
#pragma unroll
  for (int mi = 0; mi < 8; ++mi)
#pragma unroll
    for (int ni = 0; ni < 4; ++ni) acc[mi][ni] = f32x4{0.f, 0.f, 0.f, 0.f};

  // ---- prologue: K-tile 0 fully + A0/B0 of K-tile 1 in flight ----
  stA64(0, 0); stA64(0, 128); stB32(0, 0, 64); stB32(0, 128, 192);
  stA64(0, 64); stA64(0, 192); stB32(0, 32, 96); stB32(0, 160, 224);
  if (NT > 1) { stA64(1, 0); stA64(1, 128); stB32(1, 0, 64); stB32(1, 128, 192); }
  SBAR();
  asm volatile("s_waitcnt vmcnt(4)" ::: "memory");
  SBAR(); BAR();

  bf16x8 af[4][2], b0f[2][2], b1f[2][2];
  for (int t2 = 0; t2 < NT; t2 += 2) {
#pragma unroll
    for (int half = 0; half < 2; ++half) {
      const int t = t2 + half;
      u16* const Ac = AbA[half];
      u16* const Bc = BbA[half];
      const int tn = t + 1, tn2 = t + 2;
      // --- ph0: read A0+B0; stage A1(t+1)
      rdA(Ac, 0, af);
      rdB(Bc, 0, b0f);
      if (tn < NT) { stA64(tn, 64); stA64(tn, 192); }
      BAR();
      MF_CL(0, 0, af, b0f);
      BAR(); SBAR();
      // --- ph1: read B1; stage B1(t+1)
      rdB(Bc, 32, b1f);
      if (tn < NT) { stB32(tn, 32, 96); stB32(tn, 160, 224); }
      BAR();
      MF_CL(0, 1, af, b1f);
      BAR(); SBAR();
      // --- ph2: read A1; stage A0(t+2)
      rdA(Ac, 64, af);
      if (tn2 < NT) { stA64(tn2, 0); stA64(tn2, 128); }
      BAR();
      MF_CL(1, 0, af, b0f);
      BAR(); SBAR();
      // --- ph3: stage B0(t+2); boundary counted vmcnt
      if (tn2 < NT) { stB32(tn2, 0, 64); stB32(tn2, 128, 192); }
      BAR();
      MF_CL(1, 1, af, b1f);
      if (tn2 < NT) {
        asm volatile("s_waitcnt vmcnt(4)" ::: "memory");
      } else {
        asm volatile("s_waitcnt vmcnt(0)" ::: "memory");
      }
      SBAR();
      BAR(); SBAR();
    }
  }

  // ---- epilogue ----
  float bv[4];
#pragma unroll
  for (int ni = 0; ni < 4; ++ni) bv[ni] = bias[n0 + wn + (ni << 4) + c];

  if (!OUT_F32) {
    u16* Cb = (u16*)Cp;
#pragma unroll
    for (int mi = 0; mi < 8; ++mi)
#pragma unroll
      for (int ni = 0; ni < 4; ++ni)
#pragma unroll
        for (int rr = 0; rr < 4; ++rr)
          smem[(wm + (mi << 4) + (g << 2) + rr) * 256 + wn + (ni << 4) + c] =
              f2b(acc[mi][ni][rr] + bv[ni]);
    __syncthreads();
#pragma unroll
    for (int i = 0; i < 16; ++i) {
      const int idx = (i << 9) + (tid & 511);
      const int row = idx >> 5, sl = idx & 31;
      if (m0 + row < M)
        *reinterpret_cast<uint4*>(&Cb[(size_t)(m0 + row) * N + n0 + (sl << 3)]) =
            *reinterpret_cast<const uint4*>(&smem[row * 256 + (sl << 3)]);
    }
  } else {
    float* Cf = (float*)Cp;
    float* fs = (float*)smem;
#pragma unroll
    for (int hh = 0; hh < 2; ++hh) {
      __syncthreads();
      if ((w >> 2) == hh) {
#pragma unroll
        for (int mi = 0; mi < 8; ++mi)
#pragma unroll
          for (int ni = 0; ni < 4; ++ni)
#pragma unroll
            for (int rr = 0; rr < 4; ++rr)
              fs[((mi << 4) + (g << 2) + rr) * 256 + wn + (ni << 4) + c] =
                  acc[mi][ni][rr] + bv[ni];
      }
      __syncthreads();
#pragma unroll
      for (int i = 0; i < 16; ++i) {
        const int idx = (i << 9) + tid;
        const int row = idx >> 6, sl = idx & 63;
        if (m0 + (hh << 7) + row < M)
          *reinterpret_cast<float4*>(&Cf[(size_t)(m0 + (hh << 7) + row) * N + n0 + (sl << 2)]) =
              *reinterpret_cast<const float4*>(&fs[row * 256 + (sl << 2)]);
      }
    }
  }
}

// ---------------------------------------------------------------------------
// Streaming attention, swapped-operand form (proven, untouched).
// ---------------------------------------------------------------------------
#define VT_STR 200
#define PS_STR 168

template <int NKT>
DEV void attn_process(const u16* __restrict__ Qg, const u16* __restrict__ Kg,
                      u16* __restrict__ Og, const u16* Vt, u16* Pw,
                      int b, int h, int qpos0, int kpos0, int obase, int nqt,
                      int wv, int lane) {
  const int c = lane & 15, g = lane >> 4;
  constexpr float SC = 0.18033688f;  // (1/sqrt(64)) * log2(e)
  for (int qt = wv; qt < nqt; qt += 2) {
    bf16x8 aq[2];
#pragma unroll
    for (int kk = 0; kk < 2; ++kk)
      aq[kk] = *reinterpret_cast<const bf16x8*>(
          Qg + ((size_t)(b * 4096 + qpos0 + (qt << 4) + c)) * 1024 + h * 64 + (kk << 5) + (g << 3));

    f32x4 sacc[NKT];
#pragma unroll
    for (int i = 0; i < NKT; ++i) sacc[i] = f32x4{0.f, 0.f, 0.f, 0.f};
#pragma unroll
    for (int kt = 0; kt < NKT; ++kt) {
#pragma unroll
      for (int kk = 0; kk < 2; ++kk) {
        const bf16x8 bk = *reinterpret_cast<const bf16x8*>(
            Kg + ((size_t)(b * 4096 + kpos0 + (kt << 4) + c)) * 1024 + h * 64 + (kk << 5) + (g << 3));
        sacc[kt] = MFMA16(bk, aq[kk], sacc[kt], 0, 0, 0);  // S^T
      }
    }

    float mx = -3.0e38f;
#pragma unroll
    for (int kt = 0; kt < NKT; ++kt)
#pragma unroll
      for (int rr = 0; rr < 4; ++rr) mx = fmaxf(mx, sacc[kt][rr]);
    mx = fmaxf(mx, __shfl_xor(mx, 16, 64));
    mx = fmaxf(mx, __shfl_xor(mx, 32, 64));
    mx *= SC;
    float sum = 0.f;
#pragma unroll
    for (int kt = 0; kt < NKT; ++kt) {
      u16 e[4];
#pragma unroll
      for (int rr = 0; rr < 4; ++rr) {
        const float p = exp2f(sacc[kt][rr] * SC - mx);
        sum += p;
        e[rr] = f2b(p);
      }
      uint2 pk;
      pk.x = (u32)e[0] | ((u32)e[1] << 16);
      pk.y = (u32)e[2] | ((u32)e[3] << 16);
      *reinterpret_cast<uint2*>(&Pw[c * PS_STR + (kt << 4) + (g << 2)]) = pk;
    }
    sum += __shfl_xor(sum, 16, 64);
    sum += __shfl_xor(sum, 32, 64);
    const float rs = 1.f / sum;

    asm volatile("s_waitcnt lgkmcnt(0)" ::: "memory");
    __builtin_amdgcn_sched_barrier(0);

    f32x4 oacc[4];
#pragma unroll
    for (int nd = 0; nd < 4; ++nd) oacc[nd] = f32x4{0.f, 0.f, 0.f, 0.f};
#pragma unroll
    for (int u = 0; u < NKT / 2; ++u) {
      const bf16x8 pa = *reinterpret_cast<const bf16x8*>(&Pw[c * PS_STR + (u << 5) + (g << 3)]);
#pragma unroll
      for (int nd = 0; nd < 4; ++nd) {
        const int d = (nd << 4) + c;
        const int a = (u << 2) + g;
        const int us = (a & 24) | ((a ^ (d >> 3)) & 7);
        const bf16x8 vbf = *reinterpret_cast<const bf16x8*>(&Vt[d * VT_STR + (us << 3)]);
        oacc[nd] = MFMA16(vbf, pa, oacc[nd], 0, 0, 0);     // O^T
      }
    }

    const size_t orow = (size_t)(b * 3104 + obase + (qt << 4) + c);
#pragma unroll
    for (int nd = 0; nd < 4; ++nd) {
      u16 e[4];
#pragma unroll
      for (int rr = 0; rr < 4; ++rr) e[rr] = f2b(oacc[nd][rr] * rs);
      uint2 ov;
      ov.x = (u32)e[0] | ((u32)e[1] << 16);
      ov.y = (u32)e[2] | ((u32)e[3] << 16);
      *reinterpret_cast<uint2*>(&Og[orow * 1024 + h * 64 + (nd << 4) + (g << 2)]) = ov;
    }
  }
}

__global__ __launch_bounds__(128) void attn_kernel(
    const u16* __restrict__ Qg, const u16* __restrict__ Kg,
    const u16* __restrict__ Vg, u16* __restrict__ Og) {
  __shared__ u16 Vt[64 * VT_STR];
  __shared__ u16 Ps[2 * 16 * PS_STR];
  const int bid = blockIdx.x;
  const int b = bid >> 9;
  const int ch = (bid >> 4) & 31;
  const int h = bid & 15;
  const int t = threadIdx.x, wv = t >> 6, lane = t & 63;
  int qpos0, kpos0, obase, nk;
  if (ch == 0) { qpos0 = 0; kpos0 = 0; obase = 0; nk = 128; }
  else { qpos0 = (ch << 7) + 32; kpos0 = (ch << 7) - 32; obase = 128 + (ch - 1) * 96; nk = 160; }

  const size_t vbase = ((size_t)(b * 4096 + kpos0)) * 1024 + h * 64;
  const int c8 = t & 7, rg = t >> 3;
#pragma unroll
  for (int p = 0; p < 3; ++p) {
    const int k0 = (rg << 2) + (p << 6);
    if (k0 < nk) {
      u32 w[4][4];
#pragma unroll
      for (int rr = 0; rr < 4; ++rr) {
        const uint4 v = *reinterpret_cast<const uint4*>(Vg + vbase + (size_t)(k0 + rr) * 1024 + (c8 << 3));
        w[rr][0] = v.x; w[rr][1] = v.y; w[rr][2] = v.z; w[rr][3] = v.w;
      }
      const int k8 = k0 >> 3;
      const int us = (k8 & 24) | ((k8 ^ c8) & 7);
      const int base = (us << 3) + (k0 & 7);
#pragma unroll
      for (int dw = 0; dw < 4; ++dw) {
        uint2 lo, hi;
        lo.x = __builtin_amdgcn_perm(w[1][dw], w[0][dw], 0x05040100u);
        lo.y = __builtin_amdgcn_perm(w[3][dw], w[2][dw], 0x05040100u);
        hi.x = __builtin_amdgcn_perm(w[1][dw], w[0][dw], 0x07060302u);
        hi.y = __builtin_amdgcn_perm(w[3][dw], w[2][dw], 0x07060302u);
        const int d0 = (c8 << 3) + (dw << 1);
        *reinterpret_cast<uint2*>(&Vt[d0 * VT_STR + base]) = lo;
        *reinterpret_cast<uint2*>(&Vt[(d0 + 1) * VT_STR + base]) = hi;
      }
    }
  }
  __syncthreads();

  u16* Pw = Ps + wv * (16 * PS_STR);
  if (ch == 0)
    attn_process<8>(Qg, Kg, Og, Vt, Pw, b, h, qpos0, kpos0, obase, 8, wv, lane);
  else
    attn_process<10>(Qg, Kg, Og, Vt, Pw, b, h, qpos0, kpos0, obase, 6, wv, lane);
}

// ---------------------------------------------------------------------------
extern "C" void kernel_launch(void* const* d_in, const int* in_sizes, int n_in,
                              void* d_out, int out_size, void* d_ws, size_t ws_size,
                              hipStream_t stream) {
  (void)in_sizes; (void)n_in; (void)out_size;
  const float* query  = (const float*)d_in[0];
  const float* key_in = (const float*)d_in[1];
  const float* value  = (const float*)d_in[2];
  const float* Wq = (const float*)d_in[3];
  const float* bq = (const float*)d_in[4];
  const float* Wk = (const float*)d_in[5];
  const float* bk = (const float*)d_in[6];
  const float* Wv = (const float*)d_in[7];
  const float* bv = (const float*)d_in[8];
  const float* Wo = (const float*)d_in[9];
  const float* bo = (const float*)d_in[10];

  char* ws = (char*)d_ws;
  const size_t WSZ = 2097152;     // 1024*1024*2
  const size_t ASZ = 33554432;    // 16384*1024*2
  u16* WtQ = (u16*)(ws + 0 * WSZ);
  u16* WtK = (u16*)(ws + 1 * WSZ);
  u16* WtV = (u16*)(ws + 2 * WSZ);
  u16* WtO = (u16*)(ws + 3 * WSZ);
  u16* s0  = (u16*)(ws + 4 * WSZ);                // qc -> ao (serial reuse)
  u16* qb  = (u16*)(ws + 4 * WSZ + 1 * ASZ);
  u16* kb  = (u16*)(ws + 4 * WSZ + 2 * ASZ);
  u16* s3  = (u16*)(ws + 4 * WSZ + 3 * ASZ);      // kc -> vb (serial reuse)
  if (ws_size < (size_t)142606336) return;

  u16* qc = s0;                 // query bf16 (precvt; dead after gemmQ)
  u16* kc = s3;                 // key bf16 (gemmQ cvt waves; dead after gemmK)
  u16* vc = (u16*)d_out;        // value bf16 in d_out scratch (gemmK cvt waves;
                                //   dead after gemmV; gemmO overwrites d_out)
  u16* vb = s3;
  u16* ao = s0;                 // attn out (qc dead)

  precvt<<<3072, 256, 0, stream>>>(Wq, Wk, Wv, Wo, WtQ, WtK, WtV, WtO,
                                   (const float4*)query, (uint4*)qc);

  gemm256<1, 0><<<256, 640, 0, stream>>>(qc, WtQ, bq, qb,
                                         (const float4*)key_in, (uint2*)kc,
                                         16384, 1024, 1024);
  gemm256<1, 0><<<256, 640, 0, stream>>>(kc, WtK, bk, kb,
                                         (const float4*)value, (uint2*)vc,
                                         16384, 1024, 1024);
  gemm256<0, 0><<<256, 512, 0, stream>>>(vc, WtV, bv, vb,
                                         nullptr, nullptr, 16384, 1024, 1024);

  attn_kernel<<<2048, 128, 0, stream>>>(qb, kb, vb, ao);

  gemm256<0, 1><<<196, 512, 0, stream>>>(ao, WtO, bo, (float*)d_out,
                                         nullptr, nullptr, 12416, 1024, 1024);
}

// Round 13
// 385.541 us; speedup vs baseline: 1.7120x; 1.7120x over previous
//
#include <hip/hip_runtime.h>
#include <hip/hip_bf16.h>

typedef __bf16 bf16x8 __attribute__((ext_vector_type(8)));
typedef float f32x4 __attribute__((ext_vector_type(4)));
typedef unsigned short u16;
typedef unsigned int u32;

#define DEV __device__ __forceinline__
#define MFMA16 __builtin_amdgcn_mfma_f32_16x16x32_bf16

DEV u16 f2b(float f) {
  __hip_bfloat16 h = __float2bfloat16(f);
  return __builtin_bit_cast(u16, h);
}
DEV u32 pk2(float x, float y) { return (u32)f2b(x) | ((u32)f2b(y) << 16); }

DEV void gl_lds16(const u16* g, u16* l) {
  __builtin_amdgcn_global_load_lds(
      (const __attribute__((address_space(1))) void*)g,
      (__attribute__((address_space(3))) void*)l, 16, 0, 0);
}

// ---------------------------------------------------------------------------
// Weight convert+transpose: 4 weights, 256 blocks each.
// ---------------------------------------------------------------------------
__global__ __launch_bounds__(256) void wcvt_w(
    const float* __restrict__ Wq, const float* __restrict__ Wk,
    const float* __restrict__ Wv, const float* __restrict__ Wo,
    u16* __restrict__ WtQ, u16* __restrict__ WtK,
    u16* __restrict__ WtV, u16* __restrict__ WtO) {
  __shared__ u16 ls[64 * 80];
  const int t = threadIdx.x;
  const int bid = blockIdx.x;
  const int wsel = bid >> 8;
  const float* W = (wsel == 0) ? Wq : (wsel == 1) ? Wk : (wsel == 2) ? Wv : Wo;
  u16* Wt = (wsel == 0) ? WtQ : (wsel == 1) ? WtK : (wsel == 2) ? WtV : WtO;
  const int tb = bid & 255;
  const int bn = (tb & 15) << 6;
  const int bk = (tb >> 4) << 6;
#pragma unroll
  for (int rr = 0; rr < 4; ++rr) {
    const int r = (t >> 4) + (rr << 4);
    const int cc = (t & 15) << 2;
    const float4 v = *reinterpret_cast<const float4*>(&W[(size_t)(bk + r) * 1024 + bn + cc]);
    ls[(cc + 0) * 80 + r] = f2b(v.x);
    ls[(cc + 1) * 80 + r] = f2b(v.y);
    ls[(cc + 2) * 80 + r] = f2b(v.z);
    ls[(cc + 3) * 80 + r] = f2b(v.w);
  }
  __syncthreads();
#pragma unroll
  for (int it = 0; it < 2; ++it) {
    const int idx = t + (it << 8);
    const int n = idx >> 3, c8 = idx & 7;
    const uint4 o = *reinterpret_cast<const uint4*>(&ls[n * 80 + (c8 << 3)]);
    *reinterpret_cast<uint4*>(&Wt[(size_t)(bn + n) * 1024 + bk + (c8 << 3)]) = o;
  }
}

// ---------------------------------------------------------------------------
// q/k/v f32 -> bf16 (round-10 form; at its measured ~3.5 TB/s plateau).
// ---------------------------------------------------------------------------
__global__ __launch_bounds__(256) void cvt3(
    const float4* __restrict__ q, uint4* __restrict__ qo,
    const float4* __restrict__ k, uint4* __restrict__ ko,
    const float4* __restrict__ v, uint4* __restrict__ vo) {
  const int seg = (int)blockIdx.x >> 11;          // 0=q 1=k 2=v
  const int blk = (int)blockIdx.x & 2047;
  const int t = (int)threadIdx.x;
  const float4* __restrict__ src = (seg == 0) ? q : (seg == 1) ? k : v;
  uint4* __restrict__ dst = (seg == 0) ? qo : (seg == 1) ? ko : vo;
  float4 a[8];
#pragma unroll
  for (int c = 0; c < 4; ++c) {
    const size_t fi = (size_t)blk * 2048 + (size_t)((c << 8) + t) * 2;
    a[2 * c]     = src[fi];
    a[2 * c + 1] = src[fi + 1];
  }
  __builtin_amdgcn_sched_barrier(0);
#pragma unroll
  for (int c = 0; c < 4; ++c) {
    uint4 o;
    o.x = pk2(a[2 * c].x, a[2 * c].y);
    o.y = pk2(a[2 * c].z, a[2 * c].w);
    o.z = pk2(a[2 * c + 1].x, a[2 * c + 1].y);
    o.w = pk2(a[2 * c + 1].z, a[2 * c + 1].w);
    dst[(size_t)blk * 1024 + (c << 8) + t] = o;
  }
}

// ---------------------------------------------------------------------------
// 256x256-tile 8-wave GEMM.  Same barrier/vmcnt skeleton as the proven
// round-10 kernel; NEW: all 24 frag ds_reads issue at ph0 (order pinned by
// sched_barrier between groups), per-phase waits become counted lgkmcnt
// {12,8,0,0} so ph1-ph3 read latency hides under ph0-ph2 MFMA.  DS ops
// complete in order -> wait(12) = af+b0f ready, wait(8) = +b1f ready.
// ---------------------------------------------------------------------------
#define MF_CLW(LK, PR, PC, AF, BF)                                             \
  asm volatile("s_waitcnt lgkmcnt(" #LK ")" ::: "memory");                     \
  __builtin_amdgcn_sched_barrier(0);                                           \
  __builtin_amdgcn_s_setprio(1);                                               \
  _Pragma("unroll") for (int i = 0; i < 4; ++i)                                \
  _Pragma("unroll") for (int j = 0; j < 2; ++j) {                              \
    acc[(PR)*4 + i][(PC)*2 + j] =                                              \
        MFMA16(AF[i][0], BF[j][0], acc[(PR)*4 + i][(PC)*2 + j], 0, 0, 0);      \
    acc[(PR)*4 + i][(PC)*2 + j] =                                              \
        MFMA16(AF[i][1], BF[j][1], acc[(PR)*4 + i][(PC)*2 + j], 0, 0, 0);      \
  }                                                                            \
  __builtin_amdgcn_s_setprio(0);

#define BAR()  __builtin_amdgcn_s_barrier()
#define SBAR() __builtin_amdgcn_sched_barrier(0)

template <int OUT_F32>
__global__ __launch_bounds__(512, 2) void gemm256(
    const u16* __restrict__ A, const u16* __restrict__ Bt,
    const float* __restrict__ bias, void* __restrict__ Cp,
    const int M, const int N, const int K) {
  __shared__ u16 smem[65536];                       // 128 KiB -> 1 block/CU
  u16* const AbA[2] = {smem, smem + 16384};         // 256x64 each
  u16* const BbA[2] = {smem + 32768, smem + 49152};
  const int NT = K >> 6;
  const int tid = threadIdx.x;
  const int lane = tid & 63;
  const int w = tid >> 6;
  const int c = lane & 15, g = lane >> 4;

  const int nwg = (int)gridDim.x;
  const int q = nwg >> 3, r = nwg & 7;
  const int xcd = (int)blockIdx.x & 7, loc = (int)blockIdx.x >> 3;
  const int bid = (xcd < r ? xcd * (q + 1) : r * (q + 1) + (xcd - r) * q) + loc;
  const int ntN = N >> 8;
  const int bm = bid / ntN, bn = bid - bm * ntN;
  const int m0 = bm << 8, n0 = bn << 8;

  const int rl = lane >> 3;
  const int swc = ((lane & 7) ^ rl) << 3;           // pre-swizzled source col (elems)
  const int wrow = w << 3;
  const int wm = (w >> 2) << 7, wn = (w & 3) << 6;

  auto stA64 = [&](int t, int row0) {
    u16* b = AbA[t & 1];
    gl_lds16(A + (size_t)(m0 + row0 + wrow + rl) * K + (t << 6) + swc,
             &b[(row0 + wrow) << 6]);
  };
  auto stB32 = [&](int t, int ra, int rb) {
    u16* b = BbA[t & 1];
    const int r0 = (w < 4) ? (ra + (w << 3)) : (rb + ((w - 4) << 3));
    gl_lds16(Bt + (size_t)(n0 + r0 + rl) * K + (t << 6) + swc, &b[r0 << 6]);
  };

  const int sK0 = (g ^ (c & 7)) << 3;
  const int sK1 = ((4 + g) ^ (c & 7)) << 3;
  auto rdA = [&](u16* Ac, int poff, bf16x8 (&dst)[4][2]) {
#pragma unroll
    for (int mi = 0; mi < 4; ++mi) {
      const int ro = (wm + poff + (mi << 4) + c) << 6;
      dst[mi][0] = *reinterpret_cast<const bf16x8*>(&Ac[ro + sK0]);
      dst[mi][1] = *reinterpret_cast<const bf16x8*>(&Ac[ro + sK1]);
    }
  };
  auto rdB = [&](u16* Bc, int poff, bf16x8 (&dst)[2][2]) {
#pragma unroll
    for (int ni = 0; ni < 2; ++ni) {
      const int ro = (wn + poff + (ni << 4) + c) << 6;
      dst[ni][0] = *reinterpret_cast<const bf16x8*>(&Bc[ro + sK0]);
      dst[ni][1] = *reinterpret_cast<const bf16x8*>(&Bc[ro + sK1]);
    }
  };

  f32x4 acc[8][4];
#pragma unroll
  for (int mi = 0; mi < 8; ++mi)
#pragma unroll
    for (int ni = 0; ni < 4; ++ni) acc[mi][ni] = f32x4{0.f, 0.f, 0.f, 0.f};

  // ---- prologue: K-tile 0 fully + A0/B0 of K-tile 1 in flight ----
  stA64(0, 0); stA64(0, 128); stB32(0, 0, 64); stB32(0, 128, 192);
  stA64(0, 64); stA64(0, 192); stB32(0, 32, 96); stB32(0, 160, 224);
  if (NT > 1) { stA64(1, 0); stA64(1, 128); stB32(1, 0, 64); stB32(1, 128, 192); }
  SBAR();
  asm volatile("s_waitcnt vmcnt(4)" ::: "memory");
  SBAR(); BAR();

  bf16x8 af[4][2], af2[4][2], b0f[2][2], b1f[2][2];
  for (int t2 = 0; t2 < NT; t2 += 2) {
#pragma unroll
    for (int half = 0; half < 2; ++half) {
      const int t = t2 + half;
      u16* const Ac = AbA[half];
      u16* const Bc = BbA[half];
      const int tn = t + 1, tn2 = t + 2;
      // --- ph0: issue ALL 24 frag reads (pinned order: af, b0f, b1f, af2);
      //          stage A1(t+1)
      rdA(Ac, 0, af);   SBAR();
      rdB(Bc, 0, b0f);  SBAR();
      rdB(Bc, 32, b1f); SBAR();
      rdA(Ac, 64, af2);
      if (tn < NT) { stA64(tn, 64); stA64(tn, 192); }
      BAR();
      MF_CLW(12, 0, 0, af, b0f);      // b1f(4)+af2(8) may stay outstanding
      BAR(); SBAR();
      // --- ph1: stage B1(t+1)
      if (tn < NT) { stB32(tn, 32, 96); stB32(tn, 160, 224); }
      BAR();
      MF_CLW(8, 0, 1, af, b1f);       // af2(8) may stay outstanding
      BAR(); SBAR();
      // --- ph2: stage A0(t+2)
      if (tn2 < NT) { stA64(tn2, 0); stA64(tn2, 128); }
      BAR();
      MF_CLW(0, 1, 0, af2, b0f);
      BAR(); SBAR();
      // --- ph3: stage B0(t+2); boundary counted vmcnt
      if (tn2 < NT) { stB32(tn2, 0, 64); stB32(tn2, 128, 192); }
      BAR();
      MF_CLW(0, 1, 1, af2, b1f);
      if (tn2 < NT) {
        asm volatile("s_waitcnt vmcnt(4)" ::: "memory");
      } else {
        asm volatile("s_waitcnt vmcnt(0)" ::: "memory");
      }
      SBAR();
      BAR(); SBAR();
    }
  }

  // ---- epilogue ----
  float bv[4];
#pragma unroll
  for (int ni = 0; ni < 4; ++ni) bv[ni] = bias[n0 + wn + (ni << 4) + c];

  if (!OUT_F32) {
    u16* Cb = (u16*)Cp;
#pragma unroll
    for (int mi = 0; mi < 8; ++mi)
#pragma unroll
      for (int ni = 0; ni < 4; ++ni)
#pragma unroll
        for (int rr = 0; rr < 4; ++rr)
          smem[(wm + (mi << 4) + (g << 2) + rr) * 256 + wn + (ni << 4) + c] =
              f2b(acc[mi][ni][rr] + bv[ni]);
    __syncthreads();
#pragma unroll
    for (int i = 0; i < 16; ++i) {
      const int idx = (i << 9) + tid;
      const int row = idx >> 5, sl = idx & 31;
      if (m0 + row < M)
        *reinterpret_cast<uint4*>(&Cb[(size_t)(m0 + row) * N + n0 + (sl << 3)]) =
            *reinterpret_cast<const uint4*>(&smem[row * 256 + (sl << 3)]);
    }
  } else {
    float* Cf = (float*)Cp;
    float* fs = (float*)smem;
#pragma unroll
    for (int hh = 0; hh < 2; ++hh) {
      __syncthreads();
      if ((w >> 2) == hh) {
#pragma unroll
        for (int mi = 0; mi < 8; ++mi)
#pragma unroll
          for (int ni = 0; ni < 4; ++ni)
#pragma unroll
            for (int rr = 0; rr < 4; ++rr)
              fs[((mi << 4) + (g << 2) + rr) * 256 + wn + (ni << 4) + c] =
                  acc[mi][ni][rr] + bv[ni];
      }
      __syncthreads();
#pragma unroll
      for (int i = 0; i < 16; ++i) {
        const int idx = (i << 9) + tid;
        const int row = idx >> 6, sl = idx & 63;
        if (m0 + (hh << 7) + row < M)
          *reinterpret_cast<float4*>(&Cf[(size_t)(m0 + (hh << 7) + row) * N + n0 + (sl << 2)]) =
              *reinterpret_cast<const float4*>(&fs[row * 256 + (sl << 2)]);
      }
    }
  }
}

// ---------------------------------------------------------------------------
// Streaming attention, swapped-operand form (proven, untouched).
// ---------------------------------------------------------------------------
#define VT_STR 200
#define PS_STR 168

template <int NKT>
DEV void attn_process(const u16* __restrict__ Qg, const u16* __restrict__ Kg,
                      u16* __restrict__ Og, const u16* Vt, u16* Pw,
                      int b, int h, int qpos0, int kpos0, int obase, int nqt,
                      int wv, int lane) {
  const int c = lane & 15, g = lane >> 4;
  constexpr float SC = 0.18033688f;  // (1/sqrt(64)) * log2(e)
  for (int qt = wv; qt < nqt; qt += 2) {
    bf16x8 aq[2];
#pragma unroll
    for (int kk = 0; kk < 2; ++kk)
      aq[kk] = *reinterpret_cast<const bf16x8*>(
          Qg + ((size_t)(b * 4096 + qpos0 + (qt << 4) + c)) * 1024 + h * 64 + (kk << 5) + (g << 3));

    f32x4 sacc[NKT];
#pragma unroll
    for (int i = 0; i < NKT; ++i) sacc[i] = f32x4{0.f, 0.f, 0.f, 0.f};
#pragma unroll
    for (int kt = 0; kt < NKT; ++kt) {
#pragma unroll
      for (int kk = 0; kk < 2; ++kk) {
        const bf16x8 bk = *reinterpret_cast<const bf16x8*>(
            Kg + ((size_t)(b * 4096 + kpos0 + (kt << 4) + c)) * 1024 + h * 64 + (kk << 5) + (g << 3));
        sacc[kt] = MFMA16(bk, aq[kk], sacc[kt], 0, 0, 0);  // S^T
      }
    }

    float mx = -3.0e38f;
#pragma unroll
    for (int kt = 0; kt < NKT; ++kt)
#pragma unroll
      for (int rr = 0; rr < 4; ++rr) mx = fmaxf(mx, sacc[kt][rr]);
    mx = fmaxf(mx, __shfl_xor(mx, 16, 64));
    mx = fmaxf(mx, __shfl_xor(mx, 32, 64));
    mx *= SC;
    float sum = 0.f;
#pragma unroll
    for (int kt = 0; kt < NKT; ++kt) {
      u16 e[4];
#pragma unroll
      for (int rr = 0; rr < 4; ++rr) {
        const float p = exp2f(sacc[kt][rr] * SC - mx);
        sum += p;
        e[rr] = f2b(p);
      }
      uint2 pk;
      pk.x = (u32)e[0] | ((u32)e[1] << 16);
      pk.y = (u32)e[2] | ((u32)e[3] << 16);
      *reinterpret_cast<uint2*>(&Pw[c * PS_STR + (kt << 4) + (g << 2)]) = pk;
    }
    sum += __shfl_xor(sum, 16, 64);
    sum += __shfl_xor(sum, 32, 64);
    const float rs = 1.f / sum;

    asm volatile("s_waitcnt lgkmcnt(0)" ::: "memory");
    __builtin_amdgcn_sched_barrier(0);

    f32x4 oacc[4];
#pragma unroll
    for (int nd = 0; nd < 4; ++nd) oacc[nd] = f32x4{0.f, 0.f, 0.f, 0.f};
#pragma unroll
    for (int u = 0; u < NKT / 2; ++u) {
      const bf16x8 pa = *reinterpret_cast<const bf16x8*>(&Pw[c * PS_STR + (u << 5) + (g << 3)]);
#pragma unroll
      for (int nd = 0; nd < 4; ++nd) {
        const int d = (nd << 4) + c;
        const int a = (u << 2) + g;
        const int us = (a & 24) | ((a ^ (d >> 3)) & 7);
        const bf16x8 vbf = *reinterpret_cast<const bf16x8*>(&Vt[d * VT_STR + (us << 3)]);
        oacc[nd] = MFMA16(vbf, pa, oacc[nd], 0, 0, 0);     // O^T
      }
    }

    const size_t orow = (size_t)(b * 3104 + obase + (qt << 4) + c);
#pragma unroll
    for (int nd = 0; nd < 4; ++nd) {
      u16 e[4];
#pragma unroll
      for (int rr = 0; rr < 4; ++rr) e[rr] = f2b(oacc[nd][rr] * rs);
      uint2 ov;
      ov.x = (u32)e[0] | ((u32)e[1] << 16);
      ov.y = (u32)e[2] | ((u32)e[3] << 16);
      *reinterpret_cast<uint2*>(&Og[orow * 1024 + h * 64 + (nd << 4) + (g << 2)]) = ov;
    }
  }
}

__global__ __launch_bounds__(128) void attn_kernel(
    const u16* __restrict__ Qg, const u16* __restrict__ Kg,
    const u16* __restrict__ Vg, u16* __restrict__ Og) {
  __shared__ u16 Vt[64 * VT_STR];
  __shared__ u16 Ps[2 * 16 * PS_STR];
  const int bid = blockIdx.x;
  const int b = bid >> 9;
  const int ch = (bid >> 4) & 31;
  const int h = bid & 15;
  const int t = threadIdx.x, wv = t >> 6, lane = t & 63;
  int qpos0, kpos0, obase, nk;
  if (ch == 0) { qpos0 = 0; kpos0 = 0; obase = 0; nk = 128; }
  else { qpos0 = (ch << 7) + 32; kpos0 = (ch << 7) - 32; obase = 128 + (ch - 1) * 96; nk = 160; }

  const size_t vbase = ((size_t)(b * 4096 + kpos0)) * 1024 + h * 64;
  const int c8 = t & 7, rg = t >> 3;
#pragma unroll
  for (int p = 0; p < 3; ++p) {
    const int k0 = (rg << 2) + (p << 6);
    if (k0 < nk) {
      u32 w[4][4];
#pragma unroll
      for (int rr = 0; rr < 4; ++rr) {
        const uint4 v = *reinterpret_cast<const uint4*>(Vg + vbase + (size_t)(k0 + rr) * 1024 + (c8 << 3));
        w[rr][0] = v.x; w[rr][1] = v.y; w[rr][2] = v.z; w[rr][3] = v.w;
      }
      const int k8 = k0 >> 3;
      const int us = (k8 & 24) | ((k8 ^ c8) & 7);
      const int base = (us << 3) + (k0 & 7);
#pragma unroll
      for (int dw = 0; dw < 4; ++dw) {
        uint2 lo, hi;
        lo.x = __builtin_amdgcn_perm(w[1][dw], w[0][dw], 0x05040100u);
        lo.y = __builtin_amdgcn_perm(w[3][dw], w[2][dw], 0x05040100u);
        hi.x = __builtin_amdgcn_perm(w[1][dw], w[0][dw], 0x07060302u);
        hi.y = __builtin_amdgcn_perm(w[3][dw], w[2][dw], 0x07060302u);
        const int d0 = (c8 << 3) + (dw << 1);
        *reinterpret_cast<uint2*>(&Vt[d0 * VT_STR + base]) = lo;
        *reinterpret_cast<uint2*>(&Vt[(d0 + 1) * VT_STR + base]) = hi;
      }
    }
  }
  __syncthreads();

  u16* Pw = Ps + wv * (16 * PS_STR);
  if (ch == 0)
    attn_process<8>(Qg, Kg, Og, Vt, Pw, b, h, qpos0, kpos0, obase, 8, wv, lane);
  else
    attn_process<10>(Qg, Kg, Og, Vt, Pw, b, h, qpos0, kpos0, obase, 6, wv, lane);
}

// ---------------------------------------------------------------------------
extern "C" void kernel_launch(void* const* d_in, const int* in_sizes, int n_in,
                              void* d_out, int out_size, void* d_ws, size_t ws_size,
                              hipStream_t stream) {
  (void)in_sizes; (void)n_in; (void)out_size;
  const float* query  = (const float*)d_in[0];
  const float* key_in = (const float*)d_in[1];
  const float* value  = (const float*)d_in[2];
  const float* Wq = (const float*)d_in[3];
  const float* bq = (const float*)d_in[4];
  const float* Wk = (const float*)d_in[5];
  const float* bk = (const float*)d_in[6];
  const float* Wv = (const float*)d_in[7];
  const float* bv = (const float*)d_in[8];
  const float* Wo = (const float*)d_in[9];
  const float* bo = (const float*)d_in[10];

  char* ws = (char*)d_ws;
  const size_t WSZ = 2097152;     // 1024*1024*2
  const size_t ASZ = 33554432;    // 16384*1024*2
  u16* WtQ = (u16*)(ws + 0 * WSZ);
  u16* WtK = (u16*)(ws + 1 * WSZ);
  u16* WtV = (u16*)(ws + 2 * WSZ);
  u16* WtO = (u16*)(ws + 3 * WSZ);
  u16* s0  = (u16*)(ws + 4 * WSZ);                // qc -> ao (serial reuse)
  u16* qb  = (u16*)(ws + 4 * WSZ + 1 * ASZ);
  u16* kb  = (u16*)(ws + 4 * WSZ + 2 * ASZ);
  u16* s3  = (u16*)(ws + 4 * WSZ + 3 * ASZ);      // kc -> vb (serial reuse)
  if (ws_size < (size_t)142606336) return;

  u16* qc = s0;                 // query bf16 (dead after gemmQ)
  u16* kc = s3;                 // key bf16 (dead after gemmK; vb overwrites)
  u16* vc = (u16*)d_out;        // value bf16 in d_out scratch (33.6MB of 50.9MB;
                                //   dead after gemmV; gemmO fully overwrites d_out)
  u16* vb = s3;
  u16* ao = s0;                 // attn out (qc dead)

  cvt3<<<6144, 256, 0, stream>>>((const float4*)query, (uint4*)qc,
                                 (const float4*)key_in, (uint4*)kc,
                                 (const float4*)value, (uint4*)vc);
  wcvt_w<<<1024, 256, 0, stream>>>(Wq, Wk, Wv, Wo, WtQ, WtK, WtV, WtO);

  gemm256<0><<<256, 512, 0, stream>>>(qc, WtQ, bq, qb, 16384, 1024, 1024);
  gemm256<0><<<256, 512, 0, stream>>>(kc, WtK, bk, kb, 16384, 1024, 1024);
  gemm256<0><<<256, 512, 0, stream>>>(vc, WtV, bv, vb, 16384, 1024, 1024);

  attn_kernel<<<2048, 128, 0, stream>>>(qb, kb, vb, ao);

  gemm256<1><<<196, 512, 0, stream>>>(ao, WtO, bo, (float*)d_out, 12416, 1024, 1024);
}

// Round 14
// 233.775 us; speedup vs baseline: 2.8234x; 1.6492x over previous
//
#include <hip/hip_runtime.h>
#include <hip/hip_bf16.h>

typedef __bf16 bf16x8 __attribute__((ext_vector_type(8)));
typedef float f32x4 __attribute__((ext_vector_type(4)));
typedef unsigned short u16;
typedef unsigned int u32;

#define DEV __device__ __forceinline__
#define MFMA16 __builtin_amdgcn_mfma_f32_16x16x32_bf16

DEV u16 f2b(float f) {
  __hip_bfloat16 h = __float2bfloat16(f);
  return __builtin_bit_cast(u16, h);
}
DEV u32 pk2(float x, float y) { return (u32)f2b(x) | ((u32)f2b(y) << 16); }

DEV void gl_lds16(const u16* g, u16* l) {
  __builtin_amdgcn_global_load_lds(
      (const __attribute__((address_space(1))) void*)g,
      (__attribute__((address_space(3))) void*)l, 16, 0, 0);
}

// ---------------------------------------------------------------------------
// cvt_all: blocks 0..6143 = q/k/v f32->bf16 (round-10 cvt3, proven);
//          blocks 6144..7167 = weight transpose+cvt (4 weights x 256 tiles).
// ---------------------------------------------------------------------------
__global__ __launch_bounds__(256) void cvt_all(
    const float4* __restrict__ q, uint4* __restrict__ qo,
    const float4* __restrict__ k, uint4* __restrict__ ko,
    const float4* __restrict__ v, uint4* __restrict__ vo,
    const float* __restrict__ Wq, const float* __restrict__ Wk,
    const float* __restrict__ Wv, const float* __restrict__ Wo,
    u16* __restrict__ WtQ, u16* __restrict__ WtK,
    u16* __restrict__ WtV, u16* __restrict__ WtO) {
  __shared__ u16 ls[64 * 80];
  const int t = (int)threadIdx.x;
  if ((int)blockIdx.x < 6144) {
    const int seg = (int)blockIdx.x >> 11;        // 0=q 1=k 2=v
    const int blk = (int)blockIdx.x & 2047;
    const float4* __restrict__ src = (seg == 0) ? q : (seg == 1) ? k : v;
    uint4* __restrict__ dst = (seg == 0) ? qo : (seg == 1) ? ko : vo;
    float4 a[8];
#pragma unroll
    for (int c = 0; c < 4; ++c) {
      const size_t fi = (size_t)blk * 2048 + (size_t)((c << 8) + t) * 2;
      a[2 * c]     = src[fi];
      a[2 * c + 1] = src[fi + 1];
    }
    __builtin_amdgcn_sched_barrier(0);
#pragma unroll
    for (int c = 0; c < 4; ++c) {
      uint4 o;
      o.x = pk2(a[2 * c].x, a[2 * c].y);
      o.y = pk2(a[2 * c].z, a[2 * c].w);
      o.z = pk2(a[2 * c + 1].x, a[2 * c + 1].y);
      o.w = pk2(a[2 * c + 1].z, a[2 * c + 1].w);
      dst[(size_t)blk * 1024 + (c << 8) + t] = o;
    }
    return;
  }
  const int bid = (int)blockIdx.x - 6144;
  const int wsel = bid >> 8;
  const float* W = (wsel == 0) ? Wq : (wsel == 1) ? Wk : (wsel == 2) ? Wv : Wo;
  u16* Wt = (wsel == 0) ? WtQ : (wsel == 1) ? WtK : (wsel == 2) ? WtV : WtO;
  const int tb = bid & 255;
  const int bn = (tb & 15) << 6;
  const int bk = (tb >> 4) << 6;
#pragma unroll
  for (int rr = 0; rr < 4; ++rr) {
    const int r = (t >> 4) + (rr << 4);
    const int cc = (t & 15) << 2;
    const float4 v4 = *reinterpret_cast<const float4*>(&W[(size_t)(bk + r) * 1024 + bn + cc]);
    ls[(cc + 0) * 80 + r] = f2b(v4.x);
    ls[(cc + 1) * 80 + r] = f2b(v4.y);
    ls[(cc + 2) * 80 + r] = f2b(v4.z);
    ls[(cc + 3) * 80 + r] = f2b(v4.w);
  }
  __syncthreads();
#pragma unroll
  for (int it = 0; it < 2; ++it) {
    const int idx = t + (it << 8);
    const int n = idx >> 3, c8 = idx & 7;
    const uint4 o = *reinterpret_cast<const uint4*>(&ls[n * 80 + (c8 << 3)]);
    *reinterpret_cast<uint4*>(&Wt[(size_t)(bn + n) * 1024 + bk + (c8 << 3)]) = o;
  }
}

// ---------------------------------------------------------------------------
// 256x256-tile 8-wave 4-phase/K-tile GEMM (round-10 proven structure,
// byte-identical inner loop).  GEMM3: one launch runs all three QKV GEMMs
// (768 blocks, seg = blockIdx>>8 picks A/Bt/bias/C; no cross-dependencies)
// -- saves 2 device-drain boundaries + tail overlap.
// ---------------------------------------------------------------------------
#define MF_CL(PR, PC, AF, BF)                                                  \
  asm volatile("s_waitcnt lgkmcnt(0)" ::: "memory");                           \
  __builtin_amdgcn_sched_barrier(0);                                           \
  __builtin_amdgcn_s_setprio(1);                                               \
  _Pragma("unroll") for (int i = 0; i < 4; ++i)                                \
  _Pragma("unroll") for (int j = 0; j < 2; ++j) {                              \
    acc[(PR)*4 + i][(PC)*2 + j] =                                              \
        MFMA16(AF[i][0], BF[j][0], acc[(PR)*4 + i][(PC)*2 + j], 0, 0, 0);      \
    acc[(PR)*4 + i][(PC)*2 + j] =                                              \
        MFMA16(AF[i][1], BF[j][1], acc[(PR)*4 + i][(PC)*2 + j], 0, 0, 0);      \
  }                                                                            \
  __builtin_amdgcn_s_setprio(0);

#define BAR()  __builtin_amdgcn_s_barrier()
#define SBAR() __builtin_amdgcn_sched_barrier(0)

template <int GEMM3, int OUT_F32>
__global__ __launch_bounds__(512, 2) void gemm256(
    const u16* __restrict__ A0, const u16* __restrict__ A1, const u16* __restrict__ A2,
    const u16* __restrict__ Bt0, const u16* __restrict__ Bt1, const u16* __restrict__ Bt2,
    const float* __restrict__ bias0, const float* __restrict__ bias1, const float* __restrict__ bias2,
    void* __restrict__ Cp0, void* __restrict__ Cp1, void* __restrict__ Cp2,
    const int M, const int N, const int K) {
  __shared__ u16 smem[65536];                       // 128 KiB
  u16* const AbA[2] = {smem, smem + 16384};         // 256x64 each
  u16* const BbA[2] = {smem + 32768, smem + 49152};
  const int NT = K >> 6;
  const int tid = threadIdx.x;
  const int lane = tid & 63;
  const int w = tid >> 6;
  const int c = lane & 15, g = lane >> 4;

  const u16* A;
  const u16* Bt;
  const float* bias;
  void* Cp;
  int inner, nwg;
  if (GEMM3) {
    const int seg = (int)blockIdx.x >> 8;
    inner = (int)blockIdx.x & 255;
    nwg = 256;
    A = (seg == 0) ? A0 : (seg == 1) ? A1 : A2;
    Bt = (seg == 0) ? Bt0 : (seg == 1) ? Bt1 : Bt2;
    bias = (seg == 0) ? bias0 : (seg == 1) ? bias1 : bias2;
    Cp = (seg == 0) ? Cp0 : (seg == 1) ? Cp1 : Cp2;
  } else {
    inner = (int)blockIdx.x;
    nwg = (int)gridDim.x;
    A = A0; Bt = Bt0; bias = bias0; Cp = Cp0;
  }
  const int q = nwg >> 3, r = nwg & 7;
  const int xcd = inner & 7, loc = inner >> 3;
  const int bid = (xcd < r ? xcd * (q + 1) : r * (q + 1) + (xcd - r) * q) + loc;
  const int ntN = N >> 8;
  const int bm = bid / ntN, bn = bid - bm * ntN;
  const int m0 = bm << 8, n0 = bn << 8;

  const int rl = lane >> 3;
  const int swc = ((lane & 7) ^ rl) << 3;           // pre-swizzled source col (elems)
  const int wrow = w << 3;
  const int wm = (w >> 2) << 7, wn = (w & 3) << 6;

  auto stA64 = [&](int t, int row0) {
    u16* b = AbA[t & 1];
    gl_lds16(A + (size_t)(m0 + row0 + wrow + rl) * K + (t << 6) + swc,
             &b[(row0 + wrow) << 6]);
  };
  auto stB32 = [&](int t, int ra, int rb) {
    u16* b = BbA[t & 1];
    const int r0 = (w < 4) ? (ra + (w << 3)) : (rb + ((w - 4) << 3));
    gl_lds16(Bt + (size_t)(n0 + r0 + rl) * K + (t << 6) + swc, &b[r0 << 6]);
  };

  const int sK0 = (g ^ (c & 7)) << 3;
  const int sK1 = ((4 + g) ^ (c & 7)) << 3;
  auto rdA = [&](u16* Ac, int poff, bf16x8 (&dst)[4][2]) {
#pragma unroll
    for (int mi = 0; mi < 4; ++mi) {
      const int ro = (wm + poff + (mi << 4) + c) << 6;
      dst[mi][0] = *reinterpret_cast<const bf16x8*>(&Ac[ro + sK0]);
      dst[mi][1] = *reinterpret_cast<const bf16x8*>(&Ac[ro + sK1]);
    }
  };
  auto rdB = [&](u16* Bc, int poff, bf16x8 (&dst)[2][2]) {
#pragma unroll
    for (int ni = 0; ni < 2; ++ni) {
      const int ro = (wn + poff + (ni << 4) + c) << 6;
      dst[ni][0] = *reinterpret_cast<const bf16x8*>(&Bc[ro + sK0]);
      dst[ni][1] = *reinterpret_cast<const bf16x8*>(&Bc[ro + sK1]);
    }
  };

  f32x4 acc[8][4];
#pragma unroll
  for (int mi = 0; mi < 8; ++mi)
#pragma unroll
    for (int ni = 0; ni < 4; ++ni) acc[mi][ni] = f32x4{0.f, 0.f, 0.f, 0.f};

  // ---- prologue: K-tile 0 fully + A0/B0 of K-tile 1 in flight ----
  stA64(0, 0); stA64(0, 128); stB32(0, 0, 64); stB32(0, 128, 192);
  stA64(0, 64); stA64(0, 192); stB32(0, 32, 96); stB32(0, 160, 224);
  if (NT > 1) { stA64(1, 0); stA64(1, 128); stB32(1, 0, 64); stB32(1, 128, 192); }
  SBAR();
  asm volatile("s_waitcnt vmcnt(4)" ::: "memory");
  SBAR(); BAR();

  bf16x8 af[4][2], b0f[2][2], b1f[2][2];
  for (int t2 = 0; t2 < NT; t2 += 2) {
#pragma unroll
    for (int half = 0; half < 2; ++half) {
      const int t = t2 + half;
      u16* const Ac = AbA[half];
      u16* const Bc = BbA[half];
      const int tn = t + 1, tn2 = t + 2;
      // --- ph0: read A0+B0; stage A1(t+1)
      rdA(Ac, 0, af);
      rdB(Bc, 0, b0f);
      if (tn < NT) { stA64(tn, 64); stA64(tn, 192); }
      BAR();
      MF_CL(0, 0, af, b0f);
      BAR(); SBAR();
      // --- ph1: read B1; stage B1(t+1)
      rdB(Bc, 32, b1f);
      if (tn < NT) { stB32(tn, 32, 96); stB32(tn, 160, 224); }
      BAR();
      MF_CL(0, 1, af, b1f);
      BAR(); SBAR();
      // --- ph2: read A1; stage A0(t+2)
      rdA(Ac, 64, af);
      if (tn2 < NT) { stA64(tn2, 0); stA64(tn2, 128); }
      BAR();
      MF_CL(1, 0, af, b0f);
      BAR(); SBAR();
      // --- ph3: stage B0(t+2); boundary counted vmcnt
      if (tn2 < NT) { stB32(tn2, 0, 64); stB32(tn2, 128, 192); }
      BAR();
      MF_CL(1, 1, af, b1f);
      if (tn2 < NT) {
        asm volatile("s_waitcnt vmcnt(4)" ::: "memory");
      } else {
        asm volatile("s_waitcnt vmcnt(0)" ::: "memory");
      }
      SBAR();
      BAR(); SBAR();
    }
  }

  // ---- epilogue ----
  float bv[4];
#pragma unroll
  for (int ni = 0; ni < 4; ++ni) bv[ni] = bias[n0 + wn + (ni << 4) + c];

  if (!OUT_F32) {
    u16* Cb = (u16*)Cp;
#pragma unroll
    for (int mi = 0; mi < 8; ++mi)
#pragma unroll
      for (int ni = 0; ni < 4; ++ni)
#pragma unroll
        for (int rr = 0; rr < 4; ++rr)
          smem[(wm + (mi << 4) + (g << 2) + rr) * 256 + wn + (ni << 4) + c] =
              f2b(acc[mi][ni][rr] + bv[ni]);
    __syncthreads();
#pragma unroll
    for (int i = 0; i < 16; ++i) {
      const int idx = (i << 9) + tid;
      const int row = idx >> 5, sl = idx & 31;
      if (m0 + row < M)
        *reinterpret_cast<uint4*>(&Cb[(size_t)(m0 + row) * N + n0 + (sl << 3)]) =
            *reinterpret_cast<const uint4*>(&smem[row * 256 + (sl << 3)]);
    }
  } else {
    float* Cf = (float*)Cp;
    float* fs = (float*)smem;
#pragma unroll
    for (int hh = 0; hh < 2; ++hh) {
      __syncthreads();
      if ((w >> 2) == hh) {
#pragma unroll
        for (int mi = 0; mi < 8; ++mi)
#pragma unroll
          for (int ni = 0; ni < 4; ++ni)
#pragma unroll
            for (int rr = 0; rr < 4; ++rr)
              fs[((mi << 4) + (g << 2) + rr) * 256 + wn + (ni << 4) + c] =
                  acc[mi][ni][rr] + bv[ni];
      }
      __syncthreads();
#pragma unroll
      for (int i = 0; i < 16; ++i) {
        const int idx = (i << 9) + tid;
        const int row = idx >> 6, sl = idx & 63;
        if (m0 + (hh << 7) + row < M)
          *reinterpret_cast<float4*>(&Cf[(size_t)(m0 + (hh << 7) + row) * N + n0 + (sl << 2)]) =
              *reinterpret_cast<const float4*>(&fs[row * 256 + (sl << 2)]);
      }
    }
  }
}

// ---------------------------------------------------------------------------
// Streaming attention, swapped-operand form (proven, untouched).
// ---------------------------------------------------------------------------
#define VT_STR 200
#define PS_STR 168

template <int NKT>
DEV void attn_process(const u16* __restrict__ Qg, const u16* __restrict__ Kg,
                      u16* __restrict__ Og, const u16* Vt, u16* Pw,
                      int b, int h, int qpos0, int kpos0, int obase, int nqt,
                      int wv, int lane) {
  const int c = lane & 15, g = lane >> 4;
  constexpr float SC = 0.18033688f;  // (1/sqrt(64)) * log2(e)
  for (int qt = wv; qt < nqt; qt += 2) {
    bf16x8 aq[2];
#pragma unroll
    for (int kk = 0; kk < 2; ++kk)
      aq[kk] = *reinterpret_cast<const bf16x8*>(
          Qg + ((size_t)(b * 4096 + qpos0 + (qt << 4) + c)) * 1024 + h * 64 + (kk << 5) + (g << 3));

    f32x4 sacc[NKT];
#pragma unroll
    for (int i = 0; i < NKT; ++i) sacc[i] = f32x4{0.f, 0.f, 0.f, 0.f};
#pragma unroll
    for (int kt = 0; kt < NKT; ++kt) {
#pragma unroll
      for (int kk = 0; kk < 2; ++kk) {
        const bf16x8 bk = *reinterpret_cast<const bf16x8*>(
            Kg + ((size_t)(b * 4096 + kpos0 + (kt << 4) + c)) * 1024 + h * 64 + (kk << 5) + (g << 3));
        sacc[kt] = MFMA16(bk, aq[kk], sacc[kt], 0, 0, 0);  // S^T
      }
    }

    float mx = -3.0e38f;
#pragma unroll
    for (int kt = 0; kt < NKT; ++kt)
#pragma unroll
      for (int rr = 0; rr < 4; ++rr) mx = fmaxf(mx, sacc[kt][rr]);
    mx = fmaxf(mx, __shfl_xor(mx, 16, 64));
    mx = fmaxf(mx, __shfl_xor(mx, 32, 64));
    mx *= SC;
    float sum = 0.f;
#pragma unroll
    for (int kt = 0; kt < NKT; ++kt) {
      u16 e[4];
#pragma unroll
      for (int rr = 0; rr < 4; ++rr) {
        const float p = exp2f(sacc[kt][rr] * SC - mx);
        sum += p;
        e[rr] = f2b(p);
      }
      uint2 pk;
      pk.x = (u32)e[0] | ((u32)e[1] << 16);
      pk.y = (u32)e[2] | ((u32)e[3] << 16);
      *reinterpret_cast<uint2*>(&Pw[c * PS_STR + (kt << 4) + (g << 2)]) = pk;
    }
    sum += __shfl_xor(sum, 16, 64);
    sum += __shfl_xor(sum, 32, 64);
    const float rs = 1.f / sum;

    asm volatile("s_waitcnt lgkmcnt(0)" ::: "memory");
    __builtin_amdgcn_sched_barrier(0);

    f32x4 oacc[4];
#pragma unroll
    for (int nd = 0; nd < 4; ++nd) oacc[nd] = f32x4{0.f, 0.f, 0.f, 0.f};
#pragma unroll
    for (int u = 0; u < NKT / 2; ++u) {
      const bf16x8 pa = *reinterpret_cast<const bf16x8*>(&Pw[c * PS_STR + (u << 5) + (g << 3)]);
#pragma unroll
      for (int nd = 0; nd < 4; ++nd) {
        const int d = (nd << 4) + c;
        const int a = (u << 2) + g;
        const int us = (a & 24) | ((a ^ (d >> 3)) & 7);
        const bf16x8 vbf = *reinterpret_cast<const bf16x8*>(&Vt[d * VT_STR + (us << 3)]);
        oacc[nd] = MFMA16(vbf, pa, oacc[nd], 0, 0, 0);     // O^T
      }
    }

    const size_t orow = (size_t)(b * 3104 + obase + (qt << 4) + c);
#pragma unroll
    for (int nd = 0; nd < 4; ++nd) {
      u16 e[4];
#pragma unroll
      for (int rr = 0; rr < 4; ++rr) e[rr] = f2b(oacc[nd][rr] * rs);
      uint2 ov;
      ov.x = (u32)e[0] | ((u32)e[1] << 16);
      ov.y = (u32)e[2] | ((u32)e[3] << 16);
      *reinterpret_cast<uint2*>(&Og[orow * 1024 + h * 64 + (nd << 4) + (g << 2)]) = ov;
    }
  }
}

__global__ __launch_bounds__(128) void attn_kernel(
    const u16* __restrict__ Qg, const u16* __restrict__ Kg,
    const u16* __restrict__ Vg, u16* __restrict__ Og) {
  __shared__ u16 Vt[64 * VT_STR];
  __shared__ u16 Ps[2 * 16 * PS_STR];
  const int bid = blockIdx.x;
  const int b = bid >> 9;
  const int ch = (bid >> 4) & 31;
  const int h = bid & 15;
  const int t = threadIdx.x, wv = t >> 6, lane = t & 63;
  int qpos0, kpos0, obase, nk;
  if (ch == 0) { qpos0 = 0; kpos0 = 0; obase = 0; nk = 128; }
  else { qpos0 = (ch << 7) + 32; kpos0 = (ch << 7) - 32; obase = 128 + (ch - 1) * 96; nk = 160; }

  const size_t vbase = ((size_t)(b * 4096 + kpos0)) * 1024 + h * 64;
  const int c8 = t & 7, rg = t >> 3;
#pragma unroll
  for (int p = 0; p < 3; ++p) {
    const int k0 = (rg << 2) + (p << 6);
    if (k0 < nk) {
      u32 w[4][4];
#pragma unroll
      for (int rr = 0; rr < 4; ++rr) {
        const uint4 v = *reinterpret_cast<const uint4*>(Vg + vbase + (size_t)(k0 + rr) * 1024 + (c8 << 3));
        w[rr][0] = v.x; w[rr][1] = v.y; w[rr][2] = v.z; w[rr][3] = v.w;
      }
      const int k8 = k0 >> 3;
      const int us = (k8 & 24) | ((k8 ^ c8) & 7);
      const int base = (us << 3) + (k0 & 7);
#pragma unroll
      for (int dw = 0; dw < 4; ++dw) {
        uint2 lo, hi;
        lo.x = __builtin_amdgcn_perm(w[1][dw], w[0][dw], 0x05040100u);
        lo.y = __builtin_amdgcn_perm(w[3][dw], w[2][dw], 0x05040100u);
        hi.x = __builtin_amdgcn_perm(w[1][dw], w[0][dw], 0x07060302u);
        hi.y = __builtin_amdgcn_perm(w[3][dw], w[2][dw], 0x07060302u);
        const int d0 = (c8 << 3) + (dw << 1);
        *reinterpret_cast<uint2*>(&Vt[d0 * VT_STR + base]) = lo;
        *reinterpret_cast<uint2*>(&Vt[(d0 + 1) * VT_STR + base]) = hi;
      }
    }
  }
  __syncthreads();

  u16* Pw = Ps + wv * (16 * PS_STR);
  if (ch == 0)
    attn_process<8>(Qg, Kg, Og, Vt, Pw, b, h, qpos0, kpos0, obase, 8, wv, lane);
  else
    attn_process<10>(Qg, Kg, Og, Vt, Pw, b, h, qpos0, kpos0, obase, 6, wv, lane);
}

// ---------------------------------------------------------------------------
extern "C" void kernel_launch(void* const* d_in, const int* in_sizes, int n_in,
                              void* d_out, int out_size, void* d_ws, size_t ws_size,
                              hipStream_t stream) {
  (void)in_sizes; (void)n_in; (void)out_size;
  const float* query  = (const float*)d_in[0];
  const float* key_in = (const float*)d_in[1];
  const float* value  = (const float*)d_in[2];
  const float* Wq = (const float*)d_in[3];
  const float* bq = (const float*)d_in[4];
  const float* Wk = (const float*)d_in[5];
  const float* bk = (const float*)d_in[6];
  const float* Wv = (const float*)d_in[7];
  const float* bv = (const float*)d_in[8];
  const float* Wo = (const float*)d_in[9];
  const float* bo = (const float*)d_in[10];

  char* ws = (char*)d_ws;
  const size_t WSZ = 2097152;     // 1024*1024*2
  const size_t ASZ = 33554432;    // 16384*1024*2
  u16* WtQ = (u16*)(ws + 0 * WSZ);
  u16* WtK = (u16*)(ws + 1 * WSZ);
  u16* WtV = (u16*)(ws + 2 * WSZ);
  u16* WtO = (u16*)(ws + 3 * WSZ);
  u16* s0  = (u16*)(ws + 4 * WSZ);                // qc -> ao (serial reuse)
  u16* qb  = (u16*)(ws + 4 * WSZ + 1 * ASZ);
  u16* kb  = (u16*)(ws + 4 * WSZ + 2 * ASZ);
  u16* s3  = (u16*)(ws + 4 * WSZ + 3 * ASZ);      // kc -> vb (serial reuse)
  if (ws_size < (size_t)142606336) return;

  u16* qc = s0;                 // query bf16 (dead after gemm3's Q segment)
  u16* kc = s3;                 // key bf16 (dead after gemm3's K segment... NOTE:
                                //   vb aliases s3 and is written by gemm3's V
                                //   segment -- but kc is only read by the K
                                //   segment.  Cross-segment WAR hazard within one
                                //   launch!  -> kc must NOT alias vb.  Use d_out
                                //   scratch for vc instead and keep kc in s3,
                                //   vb in... see below: vb goes to s3 is WRONG.
  u16* vc = (u16*)d_out;        // value bf16 in d_out scratch
  u16* ao = s0;

  // gemm3 runs Q,K,V segments CONCURRENTLY -> no buffer may be both read by
  // one segment and written by another.  Reads: qc(s0), kc(s3), vc(d_out).
  // Writes: qb, kb, vb.  vb must be its own buffer: place vb after d_out's
  // vc region?  d_out holds vc (33.6MB) and is 50.9MB total -- not enough
  // for vb (33.6MB).  Instead: vb gets its own slot by overlapping ao's
  // future region: ao(s0) is only written AFTER gemm3 completes, and qc(s0)
  // is only read DURING gemm3.  vb must live until attn completes; ao is
  // written by attn... vb and qc/ao cannot share.  ws has exactly 4 big
  // slots (s0, qb, kb, s3).  Assign: qc=s0, kc=s3 read-only during gemm3;
  // writes qb, kb ok; vb -> needs 5th slot.  Solution: vb reuses d_out's
  // tail?  Too small.  => run V's GEMM separately (gemm2 for Q,K merged +
  // gemmV alone): still saves 1 boundary, zero hazards.
  u16* vb = s3;                 // written by separate gemmV AFTER gemm2(Q,K)

  cvt_all<<<7168, 256, 0, stream>>>((const float4*)query, (uint4*)qc,
                                    (const float4*)key_in, (uint4*)kc,
                                    (const float4*)value, (uint4*)vc,
                                    Wq, Wk, Wv, Wo, WtQ, WtK, WtV, WtO);

  // Q and K GEMMs merged (read qc/s0, kc/s3; write qb, kb -- disjoint).
  gemm256<1, 0><<<512, 512, 0, stream>>>(qc, kc, nullptr,
                                         WtQ, WtK, nullptr,
                                         bq, bk, nullptr,
                                         qb, kb, nullptr, 16384, 1024, 1024);
  // V GEMM separate: reads vc (d_out), writes vb (s3, overwrites dead kc).
  gemm256<0, 0><<<256, 512, 0, stream>>>(vc, nullptr, nullptr,
                                         WtV, nullptr, nullptr,
                                         bv, nullptr, nullptr,
                                         vb, nullptr, nullptr, 16384, 1024, 1024);

  attn_kernel<<<2048, 128, 0, stream>>>(qb, kb, vb, ao);

  gemm256<0, 1><<<196, 512, 0, stream>>>(ao, nullptr, nullptr,
                                         WtO, nullptr, nullptr,
                                         bo, nullptr, nullptr,
                                         (float*)d_out, nullptr, nullptr,
                                         12416, 1024, 1024);
}